// Round 8
// baseline (180.668 us; speedup 1.0000x reference)
//
#include <hip/hip_runtime.h>

#define NTOK 65536
#define DIN 128
#define DH 256
#define DOUT 128
#define NEXP 8
#define NPAIR 28
#define CAP 12288
#define TBL2 540      // 128-token tiles: 65536/128 + 28 partials
#define TAUF 5.0f
#define CSTRIDE 32    // cnt padded: one counter per 128 B

typedef __attribute__((ext_vector_type(8))) short short8;
typedef __attribute__((ext_vector_type(4))) float f32x4;

// ---- workspace layout (bytes) ----
#define OFF_CNT  0                              // 28 ints @ stride 32 ints
#define OFF_WG   4096                           // 1024 f32
#define OFF_BG   8192                           // 8 f32
#define OFF_W1F  8448                           // 8*128*256 bf16 = 524288
#define OFF_W2F  (OFF_W1F + NEXP*DIN*DH*2)      // 524288
#define OFF_L    (OFF_W2F + NEXP*DH*DOUT*2)     // 28*12288*16 = 5505024
#define OFF_STAGE (OFF_L + NPAIR*CAP*16)        // 28*12288*512 would be huge; stage = NTOK rows
#define OFF_INV  (OFF_STAGE + (size_t)NPAIR*CAP*DOUT*4)   // inv map, NTOK ints
#define WS_NEED  (OFF_INV + (size_t)NTOK*4)

__device__ __forceinline__ unsigned short f2bf(float f) {
  union { float f; unsigned u; } v; v.f = f;
  unsigned u = v.u;
  return (unsigned short)((u + 0x7FFFu + ((u >> 16) & 1u)) >> 16);
}

// packed f32x2 -> bf16x2 (RNE), single HW instr; lo = first operand
__device__ __forceinline__ unsigned pkbf(float a, float b) {
  unsigned r;
  asm("v_cvt_pk_bf16_f32 %0, %1, %2" : "=v"(r) : "v"(a), "v"(b));
  return r;
}

// ---- kernel 1: weight conversion (blocks 0..95) + gate fuse + cnt/aux zero (block 96) ----
__global__ void k_prep(const float* __restrict__ W1, const float* __restrict__ W2,
                       unsigned short* __restrict__ W1F, unsigned short* __restrict__ W2F,
                       const float* __restrict__ Wp, const float* __restrict__ bp,
                       const float* __restrict__ Ee, float* __restrict__ Wg,
                       float* __restrict__ bg, int* __restrict__ cnt,
                       float* __restrict__ aux) {
  __shared__ float sl[8704];
  int b = blockIdx.x, t = threadIdx.x;
  if (b == 96) {
    for (int i = 0; i < 32; i++) sl[t + i * 256] = Wp[t + i * 256];
    sl[8192 + t] = Ee[t];
    sl[8448 + t] = Ee[256 + t];
    __syncthreads();
    for (int i = 0; i < 4; i++) {
      int o = t + i * 256;
      int k = o >> 3, e = o & 7;
      float s = 0.f;
      #pragma unroll 8
      for (int l = 0; l < 64; l++) s += sl[k * 64 + l] * sl[8192 + l * 8 + e];
      Wg[o] = s;
    }
    if (t < 8) {
      float s = 0.f;
      for (int l = 0; l < 64; l++) s += bp[l] * sl[8192 + l * 8 + t];
      bg[t] = s;
    }
    if (t < NPAIR) cnt[t * CSTRIDE] = 0;
    if (t == 255) aux[0] = 0.f;
    return;
  }
  const float* src; unsigned short* dst;
  int stride, iters, cshift;
  if (b < 32) {
    int e = b >> 2, kk = b & 3;
    src = W1 + e * (DIN * DH) + kk * 32 * DH;
    dst = W1F + e * (DIN * DH) + kk * (32 * DH);
    stride = 257; iters = 32; cshift = 8;           // 32 x 256 slab
  } else {
    int bb = b - 32;
    int e = bb >> 3, kk = bb & 7;
    src = W2 + e * (DH * DOUT) + kk * 32 * DOUT;
    dst = W2F + e * (DH * DOUT) + kk * (32 * DOUT);
    stride = 129; iters = 16; cshift = 7;           // 32 x 128 slab
  }
  int ncols_m1 = (1 << cshift) - 1;
  for (int i = 0; i < iters; i++) {
    int idx = t + i * 256;
    int r = idx >> cshift, c = idx & ncols_m1;
    sl[r * stride + c] = src[idx];
  }
  __syncthreads();
  for (int i = 0; i < iters; i++) {
    int o = t + i * 256;                            // o = n*32 + c : frag linear
    int n = o >> 5, cc = o & 31;
    dst[o] = f2bf(sl[cc * stride + n]);
  }
}

// ---- kernel 2: gate — thread-per-token (256 blocks x 256 tokens); + inv map ----
__global__ void __launch_bounds__(256) k_gate(
    const float* __restrict__ x, const float* __restrict__ Wg, const float* __restrict__ bg,
    float* __restrict__ pout, int* __restrict__ cnt, uint4* __restrict__ lst,
    int* __restrict__ inv) {
  __shared__ float wgl[1024];
  __shared__ float bgl[8];
  __shared__ int lc[NPAIR], lb[NPAIR];
  int t = threadIdx.x, b = blockIdx.x;
  int tok = b * 256 + t;
  *(float4*)&wgl[t * 4] = ((const float4*)Wg)[t];
  if (t < 8) bgl[t] = bg[t];
  if (t < NPAIR) lc[t] = 0;
  __syncthreads();
  float acc[8];
  #pragma unroll
  for (int e = 0; e < 8; e++) acc[e] = bgl[e];
  const float4* xr = (const float4*)(x + (size_t)tok * DIN);
  #pragma unroll 4
  for (int i = 0; i < 32; i++) {
    float4 xv = xr[i];
    #pragma unroll
    for (int j = 0; j < 4; j++) {
      float xs_ = (j == 0) ? xv.x : (j == 1) ? xv.y : (j == 2) ? xv.z : xv.w;
      float4 wa = *(const float4*)&wgl[(i * 4 + j) * 8];
      float4 wb = *(const float4*)&wgl[(i * 4 + j) * 8 + 4];
      acc[0] += xs_ * wa.x; acc[1] += xs_ * wa.y; acc[2] += xs_ * wa.z; acc[3] += xs_ * wa.w;
      acc[4] += xs_ * wb.x; acc[5] += xs_ * wb.y; acc[6] += xs_ * wb.z; acc[7] += xs_ * wb.w;
    }
  }
  float p[8];
  #pragma unroll
  for (int e = 0; e < 8; e++) p[e] = 1.f / (1.f + expf(-acc[e] / TAUF));
  float* prow = pout + (size_t)tok * 8;
  #pragma unroll
  for (int e = 0; e < 8; e++) prow[e] = p[e];
  int i0 = 0; float v0 = -1.f;
  #pragma unroll
  for (int e = 0; e < 8; e++) if (p[e] > v0) { v0 = p[e]; i0 = e; }
  int i1 = -1; float v1 = -1.f;
  #pragma unroll
  for (int e = 0; e < 8; e++) if (e != i0 && p[e] > v1) { v1 = p[e]; i1 = e; }
  float s = v0 + v1 + 1e-10f;
  float w0 = v0 / s, w1 = v1 / s;
  int eA, eB; float wA, wB;
  if (i0 < i1) { eA = i0; eB = i1; wA = w0; wB = w1; }
  else         { eA = i1; eB = i0; wA = w1; wB = w0; }
  int pid = 7 * eA - (eA * (eA - 1)) / 2 + (eB - eA - 1);   // 28 unordered pairs
  union { float f; unsigned u; } ua, ub; ua.f = wA; ub.f = wB;
  unsigned wAb = ua.u, wBb = ub.u;
  unsigned pos = (unsigned)atomicAdd(&lc[pid], 1);   // LDS atomic
  __syncthreads();
  if (t < NPAIR) lb[t] = atomicAdd(&cnt[t * CSTRIDE], lc[t]);
  __syncthreads();
  int gi = lb[pid] + (int)pos;
  if (gi < CAP) lst[pid * CAP + gi] = make_uint4((unsigned)tok, wAb, wBb, 0u);
  if (inv) inv[tok] = (gi < CAP) ? (pid * CAP + gi) : 0;
}

// ---- kernel 3: expert v9 — v8 compute, STREAMING store to stage[bucket-slot].
// Each block writes a contiguous 64KB stage region (removes the random 512B
// HBM scatter that pinned every prior variant at ~1.13 TB/s). Fallback
// (staged=0): direct scatter to out, identical to v8. ----
__global__ void __launch_bounds__(256, 2) k_expert(
    const float* __restrict__ x,
    const unsigned short* __restrict__ W1F, const unsigned short* __restrict__ W2F,
    const float* __restrict__ b1, const float* __restrict__ b2,
    const int* __restrict__ cnt, const uint4* __restrict__ lst,
    float* __restrict__ out, float* __restrict__ stage, int staged) {
  __shared__ int cs[NPAIR];
  __shared__ __align__(16) unsigned short xs[128 * 136];   // 34816 B
  __shared__ __align__(16) unsigned short hs[128 * 136];   // 34816 B (one DH-half)
  __shared__ int toks[128];
  __shared__ float wabL[256];                              // [0..127]=wA, [128..255]=wB
  int t = threadIdx.x;
  int w = t >> 6, lane = t & 63;
  int q = lane >> 4, n16 = lane & 15;

  if (t < NPAIR) { int c = cnt[t * CSTRIDE]; cs[t] = (c > CAP) ? CAP : c; }
  __syncthreads();
  int gid = blockIdx.x;
  int bsel = -1, tIn = 0, cum = 0;
  #pragma unroll
  for (int bb = 0; bb < NPAIR; bb++) {
    int tb = (cs[bb] + 127) >> 7;
    if (bsel < 0 && gid < cum + tb) { bsel = bb; tIn = gid - cum; }
    cum += tb;
  }
  if (bsel < 0) return;
  int eA = 0, eB = 1;
  { int r = bsel;
    #pragma unroll
    for (int a = 0; a < 7; a++) { int span = 7 - a; if (r < span) { eA = a; eB = a + 1 + r; break; } r -= span; } }
  int start = tIn * 128;
  int cval = min(128, cs[bsel] - start);

  if (t < 128) {
    uint4 en = make_uint4(0u, 0u, 0u, 0u);
    if (t < cval) en = lst[bsel * CAP + start + t];
    toks[t] = (t < cval) ? (int)en.x : 0;
    union { unsigned u; float f; } ua, ub; ua.u = en.y; ub.u = en.z;
    wabL[t] = (t < cval) ? ua.f : 0.f;
    wabL[128 + t] = (t < cval) ? ub.f : 0.f;
  }
  __syncthreads();
  // gather 128 x rows -> bf16 LDS
  #pragma unroll
  for (int i = 0; i < 16; i++) {
    int idx = i * 256 + t;
    int r = idx >> 5, c4 = idx & 31;
    float4 f = *(const float4*)(x + (size_t)toks[r] * DIN + c4 * 4);
    unsigned u0 = pkbf(f.x, f.y);
    unsigned u1 = pkbf(f.z, f.w);
    *(uint2*)(xs + r * 136 + c4 * 4) = make_uint2(u0, u1);
  }
  __syncthreads();

  const f32x4 vz = {0.f, 0.f, 0.f, 0.f};
  f32x4 acc2[8][2];                                // [tok-16-tile][oc-16-tile], both passes
  #pragma unroll
  for (int tc = 0; tc < 8; tc++)
    #pragma unroll
    for (int nt = 0; nt < 2; nt++) acc2[tc][nt] = vz;

  #pragma unroll
  for (int pass = 0; pass < 2; pass++) {
    int e = pass ? eB : eA;
    const unsigned short* W1e = W1F + e * (DIN * DH);
    const unsigned short* W2e = W2F + e * (DH * DOUT);
    #pragma unroll
    for (int h = 0; h < 2; h++) {
      // ---- GEMM1 half: H^T tile (rows=hcol, cols=token), hcols [h*128+w*32,+32) ----
      short8 af[4][2];
      #pragma unroll
      for (int kk = 0; kk < 4; kk++)
        #pragma unroll
        for (int nt = 0; nt < 2; nt++)
          af[kk][nt] = *(const short8*)(W1e + kk * 8192 + (h * 128 + w * 32 + nt * 16 + n16) * 32 + q * 8);
      float4 b1f[2];
      #pragma unroll
      for (int nt = 0; nt < 2; nt++)
        b1f[nt] = *(const float4*)(b1 + e * DH + h * 128 + w * 32 + nt * 16 + q * 4);
      #pragma unroll
      for (int tc = 0; tc < 8; tc++) {
        short8 bx[4];
        #pragma unroll
        for (int kk = 0; kk < 4; kk++)
          bx[kk] = *(const short8*)(xs + (tc * 16 + n16) * 136 + kk * 32 + q * 8);
        f32x4 a1[2];
        a1[0] = vz; a1[1] = vz;
        #pragma unroll
        for (int kk = 0; kk < 4; kk++)
          #pragma unroll
          for (int nt = 0; nt < 2; nt++)
            a1[nt] = __builtin_amdgcn_mfma_f32_16x16x32_bf16(af[kk][nt], bx[kk], a1[nt], 0, 0, 0);
        int tok = tc * 16 + n16;
        float wv = wabL[pass * 128 + tok];
        #pragma unroll
        for (int nt = 0; nt < 2; nt++) {
          unsigned u0 = pkbf(fmaxf(a1[nt][0] + b1f[nt].x, 0.f) * wv,
                             fmaxf(a1[nt][1] + b1f[nt].y, 0.f) * wv);
          unsigned u1 = pkbf(fmaxf(a1[nt][2] + b1f[nt].z, 0.f) * wv,
                             fmaxf(a1[nt][3] + b1f[nt].w, 0.f) * wv);
          *(uint2*)(hs + tok * 136 + w * 32 + nt * 16 + q * 4) = make_uint2(u0, u1);
        }
      }
      __syncthreads();                             // hs half ready
      // ---- GEMM2 half: acc2 += W2[h-half K] (x) H-half; ocols [w*32,+32) ----
      short8 bw[4][2];
      #pragma unroll
      for (int kk = 0; kk < 4; kk++)
        #pragma unroll
        for (int nt = 0; nt < 2; nt++)
          bw[kk][nt] = *(const short8*)(W2e + (h * 4 + kk) * 4096 + (w * 32 + nt * 16 + n16) * 32 + q * 8);
      #pragma unroll
      for (int tc = 0; tc < 8; tc++) {
        short8 bh[4];
        #pragma unroll
        for (int kk = 0; kk < 4; kk++)
          bh[kk] = *(const short8*)(hs + (tc * 16 + n16) * 136 + kk * 32 + q * 8);
        #pragma unroll
        for (int kk = 0; kk < 4; kk++)
          #pragma unroll
          for (int nt = 0; nt < 2; nt++)
            acc2[tc][nt] = __builtin_amdgcn_mfma_f32_16x16x32_bf16(bw[kk][nt], bh[kk], acc2[tc][nt], 0, 0, 0);
      }
      __syncthreads();                             // hs consumed before overwrite
    }
  }
  // ---- store: staged -> contiguous stage rows (streaming); else scatter to out ----
  float4 b2a[2], b2b[2];
  #pragma unroll
  for (int nt = 0; nt < 2; nt++) {
    b2a[nt] = *(const float4*)(b2 + eA * DOUT + w * 32 + nt * 16 + q * 4);
    b2b[nt] = *(const float4*)(b2 + eB * DOUT + w * 32 + nt * 16 + q * 4);
  }
  size_t sbase = (size_t)bsel * CAP + start;
  #pragma unroll
  for (int tc = 0; tc < 8; tc++) {
    int tok = tc * 16 + n16;
    if (tok < cval) {
      float wA = wabL[tok], wB = wabL[128 + tok];
      float* orow = staged ? (stage + (sbase + tok) * DOUT + w * 32 + q * 4)
                           : (out + (size_t)toks[tok] * DOUT + w * 32 + q * 4);
      #pragma unroll
      for (int nt = 0; nt < 2; nt++) {
        float4 v;
        v.x = acc2[tc][nt][0] + wA * b2a[nt].x + wB * b2b[nt].x;
        v.y = acc2[tc][nt][1] + wA * b2a[nt].y + wB * b2b[nt].y;
        v.z = acc2[tc][nt][2] + wA * b2a[nt].z + wB * b2b[nt].z;
        v.w = acc2[tc][nt][3] + wA * b2a[nt].w + wB * b2b[nt].w;
        *(float4*)(orow + nt * 16) = v;
      }
    }
  }
}

// ---- kernel 4: permute stage -> out in ascending token order.
// Reads: random 512B rows (L3-resident stage). Writes: perfectly streaming. ----
__global__ void __launch_bounds__(256) k_perm(
    const float* __restrict__ stage, const int* __restrict__ inv,
    float* __restrict__ out) {
  int b = blockIdx.x, t = threadIdx.x;
  int tok = b * 128 + (t >> 1);
  int half = t & 1;
  int slot = inv[tok];
  const float4* src = (const float4*)(stage + (size_t)slot * DOUT) + half * 16;
  float4* dst = (float4*)(out + (size_t)tok * DOUT) + half * 16;
  #pragma unroll
  for (int i = 0; i < 16; i++) dst[i] = src[i];
}

extern "C" void kernel_launch(void* const* d_in, const int* in_sizes, int n_in,
                              void* d_out, int out_size, void* d_ws, size_t ws_size,
                              hipStream_t stream) {
  const float* x  = (const float*)d_in[0];
  const float* Wp = (const float*)d_in[1];
  const float* bp = (const float*)d_in[2];
  const float* Ee = (const float*)d_in[3];
  const float* W1 = (const float*)d_in[4];
  const float* b1 = (const float*)d_in[5];
  const float* W2 = (const float*)d_in[6];
  const float* b2 = (const float*)d_in[7];
  float* out = (float*)d_out;
  char* ws = (char*)d_ws;
  int* cnt = (int*)(ws + OFF_CNT);
  float* Wg = (float*)(ws + OFF_WG);
  float* bg = (float*)(ws + OFF_BG);
  unsigned short* W1F = (unsigned short*)(ws + OFF_W1F);
  unsigned short* W2F = (unsigned short*)(ws + OFF_W2F);
  uint4* lst = (uint4*)(ws + OFF_L);
  float* aux = out + (size_t)NTOK * DOUT;     // scalar output
  float* pout = aux + 1;                      // p_open [N,8]

  int staged = (ws_size >= (size_t)WS_NEED) ? 1 : 0;
  float* stage = staged ? (float*)(ws + OFF_STAGE) : out;
  int* inv = staged ? (int*)(ws + OFF_INV) : (int*)nullptr;

  k_prep<<<97, 256, 0, stream>>>(W1, W2, W1F, W2F, Wp, bp, Ee, Wg, bg, cnt, aux);
  k_gate<<<NTOK / 256, 256, 0, stream>>>(x, Wg, bg, pout, cnt, lst, inv);
  k_expert<<<TBL2, 256, 0, stream>>>(x, W1F, W2F, b1, b2, cnt, lst, out, stage, staged);
  if (staged) k_perm<<<NTOK / 128, 256, 0, stream>>>(stage, inv, out);
}

// Round 9
// 153.994 us; speedup vs baseline: 1.1732x; 1.1732x over previous
//
#include <hip/hip_runtime.h>

#define NTOK 65536
#define DIN 128
#define DH 256
#define DOUT 128
#define NEXP 8
#define TPB 256       // consecutive tokens per block
#define NBLK 256      // NTOK / TPB  (1 block per CU)
#define TAUF 5.0f
#define MCHUNK 96     // max expert-chunk rows (LDS hs capacity)

typedef __attribute__((ext_vector_type(8))) short short8;
typedef __attribute__((ext_vector_type(4))) float f32x4;

// ---- workspace layout (bytes) ----
#define OFF_WG   0                              // 1024 f32
#define OFF_BG   4096                           // 8 f32
#define OFF_W1F  4352                           // 8*128*256 bf16 = 524288
#define OFF_W2F  (OFF_W1F + NEXP*DIN*DH*2)      // 524288

__device__ __forceinline__ unsigned short f2bf(float f) {
  union { float f; unsigned u; } v; v.f = f;
  unsigned u = v.u;
  return (unsigned short)((u + 0x7FFFu + ((u >> 16) & 1u)) >> 16);
}

// packed f32x2 -> bf16x2 (RNE), single HW instr; lo = first operand
__device__ __forceinline__ unsigned pkbf(float a, float b) {
  unsigned r;
  asm("v_cvt_pk_bf16_f32 %0, %1, %2" : "=v"(r) : "v"(a), "v"(b));
  return r;
}

// ---- kernel 1: weight conversion (blocks 0..95) + gate fuse + aux zero (block 96) ----
// W1F layout: [e][kk 4][hc 256][kl 32]; W2F layout: [e][kk 8][oc 128][kl 32]
__global__ void k_prep(const float* __restrict__ W1, const float* __restrict__ W2,
                       unsigned short* __restrict__ W1F, unsigned short* __restrict__ W2F,
                       const float* __restrict__ Wp, const float* __restrict__ bp,
                       const float* __restrict__ Ee, float* __restrict__ Wg,
                       float* __restrict__ bg, float* __restrict__ aux) {
  __shared__ float sl[8704];
  int b = blockIdx.x, t = threadIdx.x;
  if (b == 96) {
    for (int i = 0; i < 32; i++) sl[t + i * 256] = Wp[t + i * 256];
    sl[8192 + t] = Ee[t];
    sl[8448 + t] = Ee[256 + t];
    __syncthreads();
    for (int i = 0; i < 4; i++) {
      int o = t + i * 256;
      int k = o >> 3, e = o & 7;
      float s = 0.f;
      #pragma unroll 8
      for (int l = 0; l < 64; l++) s += sl[k * 64 + l] * sl[8192 + l * 8 + e];
      Wg[o] = s;
    }
    if (t < 8) {
      float s = 0.f;
      for (int l = 0; l < 64; l++) s += bp[l] * sl[8192 + l * 8 + t];
      bg[t] = s;
    }
    if (t == 255) aux[0] = 0.f;
    return;
  }
  const float* src; unsigned short* dst;
  int stride, iters, cshift;
  if (b < 32) {
    int e = b >> 2, kk = b & 3;
    src = W1 + e * (DIN * DH) + kk * 32 * DH;
    dst = W1F + e * (DIN * DH) + kk * (32 * DH);
    stride = 257; iters = 32; cshift = 8;           // 32 x 256 slab
  } else {
    int bb = b - 32;
    int e = bb >> 3, kk = bb & 7;
    src = W2 + e * (DH * DOUT) + kk * 32 * DOUT;
    dst = W2F + e * (DH * DOUT) + kk * (32 * DOUT);
    stride = 129; iters = 16; cshift = 7;           // 32 x 128 slab
  }
  int ncols_m1 = (1 << cshift) - 1;
  for (int i = 0; i < iters; i++) {
    int idx = t + i * 256;
    int r = idx >> cshift, c = idx & ncols_m1;
    sl[r * stride + c] = src[idx];
  }
  __syncthreads();
  for (int i = 0; i < iters; i++) {
    int o = t + i * 256;                            // o = hc*32 + kl
    int n = o >> 5, cc = o & 31;
    dst[o] = f2bf(sl[cc * stride + n]);
  }
}

// ---- kernel 2: FUSED gate + expert, consecutive-token blocks (no permutation).
// 256 blocks x 512 thr (8 waves), block b owns tokens [b*256, +256).
// Phase 1: stream x -> xs(bf16) while computing gate dots (x L1-windowed).
// Phase 2: sigmoid/top-2, build per-expert LDS lists (tok | flags, w); pad to 16.
// Phase 3: per expert e (asc): chunks of <=96 rows; G1 swapped (D rows=hcol,
// cols=token) -> hs pre-scaled by gate w; G2 swapped (D rows=oc, cols=token);
// store: first-touch (e == min pair) plain float4, second-touch RMW add —
// block-local 128KB out window stays L2-resident, ordered by chunk barriers.
// Weights stream global->VGPR (L2-resident 2MB). Zero random global traffic. ----
__global__ void __launch_bounds__(512, 2) k_fused(
    const float* __restrict__ x,
    const unsigned short* __restrict__ W1F, const unsigned short* __restrict__ W2F,
    const float* __restrict__ b1, const float* __restrict__ b2,
    const float* __restrict__ Wg, const float* __restrict__ bg,
    float* __restrict__ pout, float* __restrict__ out) {
  __shared__ float wgl[1024];
  __shared__ float bgl[8];
  __shared__ __align__(16) unsigned short xs[TPB * 136];     // 69632 B
  __shared__ __align__(16) unsigned short hs[MCHUNK * 264];  // 50688 B (pg overlay)
  __shared__ unsigned short lTok[NEXP * 256];                // 4096 B
  __shared__ float lW[NEXP * 256];                           // 8192 B
  __shared__ int lcnt[NEXP], ncnt[NEXP];
  float* pg = (float*)hs;                                    // 512*8 f32 gate partials

  int t = threadIdx.x, b = blockIdx.x;
  int w = t >> 6, lane = t & 63, q = lane >> 4, n16 = lane & 15;

  if (t < 256) *(float4*)&wgl[t * 4] = ((const float4*)Wg)[t];
  if (t < 8) { bgl[t] = bg[t]; lcnt[t] = 0; }
  __syncthreads();

  // ---- phase 1: stream x (2 thr/row) -> bf16 xs + gate partial dots ----
  {
    int row = t >> 1, half = t & 1;
    const float4* xr = (const float4*)(x + ((size_t)b * TPB + row) * DIN + half * 64);
    float acc[8];
    #pragma unroll
    for (int e = 0; e < 8; e++) acc[e] = 0.f;
    #pragma unroll
    for (int j = 0; j < 16; j++) {
      float4 f = xr[j];
      int c0 = half * 64 + j * 4;
      #pragma unroll
      for (int s = 0; s < 4; s++) {
        float xv = (s == 0) ? f.x : (s == 1) ? f.y : (s == 2) ? f.z : f.w;
        float4 wa = *(const float4*)&wgl[(c0 + s) * 8];
        float4 wb = *(const float4*)&wgl[(c0 + s) * 8 + 4];
        acc[0] += xv * wa.x; acc[1] += xv * wa.y; acc[2] += xv * wa.z; acc[3] += xv * wa.w;
        acc[4] += xv * wb.x; acc[5] += xv * wb.y; acc[6] += xv * wb.z; acc[7] += xv * wb.w;
      }
      unsigned u0 = pkbf(f.x, f.y), u1 = pkbf(f.z, f.w);
      *(uint2*)(xs + row * 136 + c0) = make_uint2(u0, u1);
    }
    #pragma unroll
    for (int e = 0; e < 8; e++) pg[t * 8 + e] = acc[e];
  }
  __syncthreads();
  // ---- phase 2: gate finish, top-2, per-expert list build ----
  if (t < TPB) {
    float p[8];
    #pragma unroll
    for (int e = 0; e < 8; e++) {
      float lg = pg[(2 * t) * 8 + e] + pg[(2 * t + 1) * 8 + e] + bgl[e];
      p[e] = 1.f / (1.f + expf(-lg / TAUF));
    }
    float4* pr = (float4*)(pout + ((size_t)b * TPB + t) * 8);
    float4 pa = {p[0], p[1], p[2], p[3]}, pb = {p[4], p[5], p[6], p[7]};
    pr[0] = pa; pr[1] = pb;
    int i0 = 0; float v0 = -1.f;
    #pragma unroll
    for (int e = 0; e < 8; e++) if (p[e] > v0) { v0 = p[e]; i0 = e; }
    int i1 = -1; float v1 = -1.f;
    #pragma unroll
    for (int e = 0; e < 8; e++) if (e != i0 && p[e] > v1) { v1 = p[e]; i1 = e; }
    float s = v0 + v1 + 1e-10f;
    float w0 = v0 / s, w1 = v1 / s;
    int eMin, eMax; float wMin, wMax;
    if (i0 < i1) { eMin = i0; eMax = i1; wMin = w0; wMax = w1; }
    else         { eMin = i1; eMax = i0; wMin = w1; wMax = w0; }
    int pA = atomicAdd(&lcnt[eMin], 1);
    lTok[eMin * 256 + pA] = (unsigned short)t;              // first touch: plain store
    lW[eMin * 256 + pA] = wMin;
    int pB = atomicAdd(&lcnt[eMax], 1);
    lTok[eMax * 256 + pB] = (unsigned short)(t | 0x8000);   // second touch: RMW add
    lW[eMax * 256 + pB] = wMax;
  }
  __syncthreads();
  if (t < 8) {
    int n = lcnt[t], np = (n + 15) & ~15;
    for (int i = n; i < np; i++) { lTok[t * 256 + i] = 0x4000; lW[t * 256 + i] = 0.f; }  // dead
    ncnt[t] = np;
  }
  __syncthreads();

  // ---- phase 3: expert loop ----
  const f32x4 vz = {0.f, 0.f, 0.f, 0.f};
  for (int e = 0; e < 8; e++) {
    int npad = ncnt[e];
    const unsigned short* W1e = W1F + e * (DIN * DH);
    const unsigned short* W2e = W2F + e * (DH * DOUT);
    for (int start = 0; start < npad; start += MCHUNK) {
      int mt = (min(MCHUNK, npad - start)) >> 4;            // 1..6 token-16-tiles
      // ---- G1: hs[row=chunk-token][hcol] = w * relu(X@W1 + b1); wave w -> hcols [w*32,+32)
      short8 af[4][2];
      #pragma unroll
      for (int kk = 0; kk < 4; kk++)
        #pragma unroll
        for (int nt = 0; nt < 2; nt++)
          af[kk][nt] = *(const short8*)(W1e + kk * 8192 + (w * 32 + nt * 16 + n16) * 32 + q * 8);
      float4 b1f[2];
      #pragma unroll
      for (int nt = 0; nt < 2; nt++)
        b1f[nt] = *(const float4*)(b1 + e * DH + w * 32 + nt * 16 + q * 4);
      #pragma unroll
      for (int tc = 0; tc < 6; tc++) {
        if (tc < mt) {
          int ce = e * 256 + start + tc * 16 + n16;
          int xrow = lTok[ce] & 0x3FF;
          float wv = lW[ce];
          short8 bx[4];
          #pragma unroll
          for (int kk = 0; kk < 4; kk++)
            bx[kk] = *(const short8*)(xs + xrow * 136 + kk * 32 + q * 8);
          f32x4 a1[2]; a1[0] = vz; a1[1] = vz;
          #pragma unroll
          for (int kk = 0; kk < 4; kk++)
            #pragma unroll
            for (int nt = 0; nt < 2; nt++)
              a1[nt] = __builtin_amdgcn_mfma_f32_16x16x32_bf16(af[kk][nt], bx[kk], a1[nt], 0, 0, 0);
          #pragma unroll
          for (int nt = 0; nt < 2; nt++) {
            unsigned u0 = pkbf(fmaxf(a1[nt][0] + b1f[nt].x, 0.f) * wv,
                               fmaxf(a1[nt][1] + b1f[nt].y, 0.f) * wv);
            unsigned u1 = pkbf(fmaxf(a1[nt][2] + b1f[nt].z, 0.f) * wv,
                               fmaxf(a1[nt][3] + b1f[nt].w, 0.f) * wv);
            *(uint2*)(hs + (tc * 16 + n16) * 264 + w * 32 + nt * 16 + q * 4) = make_uint2(u0, u1);
          }
        }
      }
      __syncthreads();                                      // hs ready
      // ---- G2: D[row=oc][col=token]; wave w -> ocols [w*16,+16), K=256
      short8 bw[8];
      #pragma unroll
      for (int kk = 0; kk < 8; kk++)
        bw[kk] = *(const short8*)(W2e + kk * 4096 + (w * 16 + n16) * 32 + q * 8);
      float4 b2f = *(const float4*)(b2 + e * DOUT + w * 16 + q * 4);
      #pragma unroll
      for (int tc = 0; tc < 6; tc++) {
        if (tc < mt) {
          short8 ah[8];
          #pragma unroll
          for (int kk = 0; kk < 8; kk++)
            ah[kk] = *(const short8*)(hs + (tc * 16 + n16) * 264 + kk * 32 + q * 8);
          f32x4 a2 = vz;
          #pragma unroll
          for (int kk = 0; kk < 8; kk++)
            a2 = __builtin_amdgcn_mfma_f32_16x16x32_bf16(bw[kk], ah[kk], a2, 0, 0, 0);
          int ce = e * 256 + start + tc * 16 + n16;
          unsigned entry = lTok[ce];
          if (!(entry & 0x4000)) {
            float wv = lW[ce];
            float4 v;
            v.x = a2[0] + wv * b2f.x; v.y = a2[1] + wv * b2f.y;
            v.z = a2[2] + wv * b2f.z; v.w = a2[3] + wv * b2f.w;
            float* pp = out + ((size_t)b * TPB + (entry & 0x3FF)) * DOUT + w * 16 + q * 4;
            if (entry & 0x8000) {                           // second touch: barrier-ordered RMW
              float4 o = *(const float4*)pp;
              v.x += o.x; v.y += o.y; v.z += o.z; v.w += o.w;
            }
            *(float4*)pp = v;
          }
        }
      }
      __syncthreads();                                      // stores drained before hs reuse
    }
  }
}

extern "C" void kernel_launch(void* const* d_in, const int* in_sizes, int n_in,
                              void* d_out, int out_size, void* d_ws, size_t ws_size,
                              hipStream_t stream) {
  const float* x  = (const float*)d_in[0];
  const float* Wp = (const float*)d_in[1];
  const float* bp = (const float*)d_in[2];
  const float* Ee = (const float*)d_in[3];
  const float* W1 = (const float*)d_in[4];
  const float* b1 = (const float*)d_in[5];
  const float* W2 = (const float*)d_in[6];
  const float* b2 = (const float*)d_in[7];
  float* out = (float*)d_out;
  char* ws = (char*)d_ws;
  float* Wg = (float*)(ws + OFF_WG);
  float* bg = (float*)(ws + OFF_BG);
  unsigned short* W1F = (unsigned short*)(ws + OFF_W1F);
  unsigned short* W2F = (unsigned short*)(ws + OFF_W2F);
  float* aux = out + (size_t)NTOK * DOUT;     // scalar output
  float* pout = aux + 1;                      // p_open [N,8]

  k_prep<<<97, 256, 0, stream>>>(W1, W2, W1F, W2F, Wp, bp, Ee, Wg, bg, aux);
  k_fused<<<NBLK, 512, 0, stream>>>(x, W1F, W2F, b1, b2, Wg, bg, pout, out);
}